// Round 2
// baseline (115.412 us; speedup 1.0000x reference)
//
#include <hip/hip_runtime.h>
#include <hip/hip_fp16.h>

#define GYD 512
#define GXD 512
#define HD 256
#define WD 256
#define BD 8
#define NSAMP 100000
#define JD 7

// LDS layout for 4-batch interleave: addr(x, c) = 4*(x + (x>>3)) + c.
// Verified per-wave bank math: all three radix-8 stages read/write at <=2-way
// aliasing (free on CDNA4); only the one-time init scatter is 8-way.
#define LDSZ 2304   // LPF(511)+3 = 2299, rounded up

__device__ __forceinline__ int LPF(int x) { return (x + (x >> 3)) << 2; }

// digit-reverse base 8, 3 digits (involution)
__device__ __forceinline__ int dr3(int i) {
    return ((i & 7) << 6) | (i & 56) | ((i >> 6) & 7);
}

// One radix-8 DIT stage over 4 interleaved 512-pt FFTs in LDS.
// 256 threads: c = t&3 (batch), m = t>>2 (butterfly 0..63).
// ZHI: inputs j=4..7 structurally zero (zero-padded upper half, stage 1 only).
template<int LEN, int EIGHTH, int TWSH, bool ZHI>
__device__ __forceinline__ void r8s(float* __restrict__ re, float* __restrict__ im,
                                    const float* __restrict__ twr,
                                    const float* __restrict__ twi, int t) {
    const int c = t & 3;
    const int m = t >> 2;                    // 0..63
    const int off = m & (EIGHTH - 1);
    const int blk = m / EIGHTH;
    const int x0 = blk * LEN + off;
    int p[8];
    #pragma unroll
    for (int j = 0; j < 8; ++j) p[j] = LPF(x0 + j * EIGHTH) + c;

    float E0r, E0i, E1r, E1i, E2r, E2i, E3r, E3i;
    float O0r, O0i, O1r, O1i, O2r, O2i, O3r, O3i;

    if (ZHI) {
        // a4..a7 == 0: evens reduce to {a0,a2}, odds to {a1,a3}.
        const float a0r = re[p[0]], a0i = im[p[0]];
        const float a1r = re[p[1]], a1i = im[p[1]];
        const float a2r = re[p[2]], a2i = im[p[2]];
        const float a3r = re[p[3]], a3i = im[p[3]];
        E0r = a0r + a2r; E0i = a0i + a2i;
        E2r = a0r - a2r; E2i = a0i - a2i;
        E1r = a0r + a2i; E1i = a0i - a2r;     // a0 - i*a2
        E3r = a0r - a2i; E3i = a0i + a2r;     // a0 + i*a2
        O0r = a1r + a3r; O0i = a1i + a3i;
        O2r = a1r - a3r; O2i = a1i - a3i;
        O1r = a1r + a3i; O1i = a1i - a3r;     // a1 - i*a3
        O3r = a1r - a3i; O3i = a1i + a3r;     // a1 + i*a3
    } else {
        float ar[8], ai[8];
        #pragma unroll
        for (int j = 0; j < 8; ++j) {
            ar[j] = re[p[j]];
            ai[j] = im[p[j]];
        }
        if (TWSH >= 0) {
            #pragma unroll
            for (int j = 1; j < 8; ++j) {
                const int idx = (off * j) << (TWSH >= 0 ? TWSH : 0);
                const float cr = twr[idx], ci = twi[idx];
                const float tr = ar[j] * cr - ai[j] * ci;
                ai[j] = ar[j] * ci + ai[j] * cr;
                ar[j] = tr;
            }
        }
        const float e0r = ar[0] + ar[4], e0i = ai[0] + ai[4];
        const float e1r = ar[0] - ar[4], e1i = ai[0] - ai[4];
        const float e2r = ar[2] + ar[6], e2i = ai[2] + ai[6];
        const float e3r = ar[2] - ar[6], e3i = ai[2] - ai[6];
        E0r = e0r + e2r; E0i = e0i + e2i;
        E2r = e0r - e2r; E2i = e0i - e2i;
        E1r = e1r + e3i; E1i = e1i - e3r;     // e1 - i*e3
        E3r = e1r - e3i; E3i = e1i + e3r;     // e1 + i*e3

        const float q0r = ar[1] + ar[5], q0i = ai[1] + ai[5];
        const float q1r = ar[1] - ar[5], q1i = ai[1] - ai[5];
        const float q2r = ar[3] + ar[7], q2i = ai[3] + ai[7];
        const float q3r = ar[3] - ar[7], q3i = ai[3] - ai[7];
        O0r = q0r + q2r; O0i = q0i + q2i;
        O2r = q0r - q2r; O2i = q0i - q2i;
        O1r = q1r + q3i; O1i = q1i - q3r;
        O3r = q1r - q3i; O3i = q1i + q3r;
    }

    const float S = 0.70710678118654752f;
    const float T0r = O0r,              T0i = O0i;
    const float T1r = S * (O1r + O1i),  T1i = S * (O1i - O1r);
    const float T2r = O2i,              T2i = -O2r;
    const float T3r = S * (O3i - O3r),  T3i = -S * (O3r + O3i);

    re[p[0]] = E0r + T0r;  im[p[0]] = E0i + T0i;
    re[p[4]] = E0r - T0r;  im[p[4]] = E0i - T0i;
    re[p[1]] = E1r + T1r;  im[p[1]] = E1i + T1i;
    re[p[5]] = E1r - T1r;  im[p[5]] = E1i - T1i;
    re[p[2]] = E2r + T2r;  im[p[2]] = E2i + T2i;
    re[p[6]] = E2r - T2r;  im[p[6]] = E2i - T2i;
    re[p[3]] = E3r + T3r;  im[p[3]] = E3i + T3i;
    re[p[7]] = E3r - T3r;  im[p[7]] = E3i - T3i;
}

// Kernel A: apodized zero-padded row FFT. Block = (row y, batch-half bh):
// 512 blocks x 256 threads -> 2 blocks/CU co-resident (was 1) so independent
// barrier groups overlap each other's LDS/waitcnt stalls.
// Output G1h fp16, layout [y][bh][x] float4 (4 half2 = 4 batches) -> pack
// writes fully coalesced.
__global__ __launch_bounds__(256, 2) void rowfft_kernel(
    const float* __restrict__ xr, const float* __restrict__ xi,
    const float* __restrict__ sc_y, const float* __restrict__ sc_x,
    float4* __restrict__ G1h4)
{
    __shared__ float re[LDSZ];
    __shared__ float im[LDSZ];
    __shared__ float twr[512];
    __shared__ float twi[512];
    const int t = threadIdx.x;
    const int y = blockIdx.x >> 1;
    const int bh = blockIdx.x & 1;

    #pragma unroll
    for (int k = t; k < 512; k += 256) {      // tw[m] = exp(-2*pi*i*m/512)
        float sn, cs;
        sincospif(-(float)k / 256.0f, &sn, &cs);
        twr[k] = cs; twi[k] = sn;
    }

    const float sy = sc_y[y];
    {
        const int c = t >> 6;                 // local batch 0..3 (wave-uniform)
        const int x4 = (t & 63) << 2;         // coalesced float4 per batch
        const int gb = bh * 4 + c;
        const float4 vr = *(const float4*)(xr + gb * (HD * WD) + y * WD + x4);
        const float4 vi = *(const float4*)(xi + gb * (HD * WD) + y * WD + x4);
        const float4 sx = *(const float4*)(sc_x + x4);
        int p;
        float s;
        s = sy * sx.x; p = LPF(dr3(x4 + 0)) + c; re[p] = vr.x * s; im[p] = vi.x * s;
        s = sy * sx.y; p = LPF(dr3(x4 + 1)) + c; re[p] = vr.y * s; im[p] = vi.y * s;
        s = sy * sx.z; p = LPF(dr3(x4 + 2)) + c; re[p] = vr.z * s; im[p] = vi.z * s;
        s = sy * sx.w; p = LPF(dr3(x4 + 3)) + c; re[p] = vr.w * s; im[p] = vi.w * s;
        // upper half (x 256..511) structurally zero: lands at X&7 >= 4,
        // never written, consumed only by the ZHI stage 1.
    }
    __syncthreads();
    r8s<8, 1, -1, true>(re, im, twr, twi, t);
    __syncthreads();
    r8s<64, 8, 3, false>(re, im, twr, twi, t);
    __syncthreads();
    r8s<512, 64, 0, false>(re, im, twr, twi, t);
    __syncthreads();

    // fp16 pack: [y][bh][x], one float4 (4 batches) per x, coalesced.
    float4* dst = G1h4 + (size_t)y * 1024 + (size_t)bh * 512;
    #pragma unroll
    for (int iter = 0; iter < 2; ++iter) {
        const int x = iter * 256 + t;         // 0..511
        const int base = LPF(x);
        union { __half2 h[4]; float4 f4; } u;
        #pragma unroll
        for (int ii = 0; ii < 4; ++ii) {
            const int cc = (ii + x) & 3;      // i-rotation: 2-way banks not 8-way
            u.h[cc] = __floats2half2_rn(re[base + cc], im[base + cc]);
        }
        dst[x] = u.f4;
    }
}

// Kernel B: zero-padded column FFT. Block = (col x, batch-half bh):
// 1024 blocks x 256 threads -> 4 blocks/CU co-resident (launch_bounds caps
// VGPR at 128 to guarantee it). fp16 in (G1h [y][bh][x]), fp16 out (ghat,
// batch-interleaved half2, same layout the gather consumes).
__global__ __launch_bounds__(256, 4) void colfft_kernel(
    const float4* __restrict__ G1h4, float2* __restrict__ ghat_f2)
{
    __shared__ float re[LDSZ];
    __shared__ float im[LDSZ];
    __shared__ float twr[512];
    __shared__ float twi[512];
    const int t = threadIdx.x;
    const int x = blockIdx.x >> 1;
    const int bh = blockIdx.x & 1;

    #pragma unroll
    for (int k = t; k < 512; k += 256) {
        float sn, cs;
        sincospif(-(float)k / 256.0f, &sn, &cs);
        twr[k] = cs; twi[k] = sn;
    }

    {   // thread t owns LDS target slot X (X&7 < 4); source row yy = dr3(X).
        // Global read is inherently strided (transpose side); LDS write is the
        // side we keep conflict-light (b128-equivalent, 2-way).
        const int q = t >> 2, r = t & 3;
        const int X = (q << 3) | r;           // the 256 ZHI-live slots
        const int yy = dr3(X);                // 0..255, bijective
        union { __half2 h[4]; float4 f4; } u;
        u.f4 = G1h4[(size_t)yy * 1024 + (size_t)bh * 512 + x];
        const int base = LPF(X);
        #pragma unroll
        for (int i = 0; i < 4; ++i) {
            const float2 v = __half22float2(u.h[i]);
            re[base + i] = v.x;
            im[base + i] = v.y;
        }
        // y 256..511 structurally zero (slots X&7 >= 4): never written.
    }
    __syncthreads();
    r8s<8, 1, -1, true>(re, im, twr, twi, t);
    __syncthreads();
    r8s<64, 8, 3, false>(re, im, twr, twi, t);
    __syncthreads();
    r8s<512, 64, 0, false>(re, im, twr, twi, t);
    __syncthreads();

    const float scale = 1.0f / 512.0f;        // ortho: 1/sqrt(512*512)
    #pragma unroll
    for (int iter = 0; iter < 4; ++iter) {
        const int idx = iter * 256 + t;       // 0..1023 = 512 y x 2 pairs
        const int yy = idx >> 1;
        const int k  = idx & 1;               // local batch pair
        const int p = LPF(yy) + (k << 1);
        union { __half2 h[2]; float2 f; } u;
        u.h[0] = __floats2half2_rn(re[p] * scale,     im[p] * scale);
        u.h[1] = __floats2half2_rn(re[p + 1] * scale, im[p + 1] * scale);
        ghat_f2[((size_t)yy * GXD + x) * 4 + bh * 2 + k] = u.f;
    }
}

// Kernel C: 7x7 KB gather on fp16 interleaved ghat -- UNCHANGED (previous
// session ablated this: 8 lanes/sample, half2/tap, max TLP measured best).
__global__ __launch_bounds__(256) void gather_kernel(
    const __half2* __restrict__ gh,
    const float* __restrict__ wy, const float* __restrict__ wx,
    const float* __restrict__ phr, const float* __restrict__ phi,
    const int* __restrict__ iy, const int* __restrict__ ix,
    float2* __restrict__ out)
{
    __shared__ int   s_iy[32 * JD];
    __shared__ int   s_ix[32 * JD];
    __shared__ float s_wy[32 * JD];
    __shared__ float s_wx[32 * JD];
    __shared__ float s_pr[32];
    __shared__ float s_pi[32];
    const int t = threadIdx.x;
    const int n0 = blockIdx.x * 32;          // 3125 * 32 = 100000 exact

    if (t < 224) {                           // 32 samples x 7 taps, coalesced
        const int g = n0 * JD + t;
        s_iy[t] = iy[g];
        s_ix[t] = ix[g];
        s_wy[t] = wy[g];
        s_wx[t] = wx[g];
    } else {                                 // threads 224..255: phase
        const int s = t - 224;
        s_pr[s] = phr[n0 + s];
        s_pi[s] = phi[n0 + s];
    }
    __syncthreads();

    const int b = t & 7;
    const int s = t >> 3;                    // local sample 0..31
    const int base = s * JD;

    int iyl[JD], ixl[JD];
    float wyl[JD], wxl[JD];
    #pragma unroll
    for (int j = 0; j < JD; ++j) {
        iyl[j] = s_iy[base + j];
        ixl[j] = s_ix[base + j];
        wyl[j] = s_wy[base + j];
        wxl[j] = s_wx[base + j];
    }

    float ar = 0.0f, ai = 0.0f;
    #pragma unroll
    for (int j = 0; j < JD; ++j) {
        const int rowoff = iyl[j] * GXD;
        const float wj = wyl[j];
        #pragma unroll
        for (int k = 0; k < JD; ++k) {
            const float w = wj * wxl[k];
            const float2 v = __half22float2(gh[(size_t)(rowoff + ixl[k]) * BD + b]);
            ar += v.x * w;
            ai += v.y * w;
        }
    }

    const int n = n0 + s;
    const float pr = s_pr[s], pi = s_pi[s];
    out[(size_t)b * NSAMP + n] = make_float2(ar * pr - ai * pi,
                                             ar * pi + ai * pr);
}

extern "C" void kernel_launch(void* const* d_in, const int* in_sizes, int n_in,
                              void* d_out, int out_size, void* d_ws, size_t ws_size,
                              hipStream_t stream) {
    const float* xr   = (const float*)d_in[0];
    const float* xi   = (const float*)d_in[1];
    const float* sc_y = (const float*)d_in[2];
    const float* sc_x = (const float*)d_in[3];
    const float* wy   = (const float*)d_in[4];
    const float* wx   = (const float*)d_in[5];
    const float* phr  = (const float*)d_in[6];
    const float* phi  = (const float*)d_in[7];
    const int*   iy   = (const int*)d_in[8];
    const int*   ix   = (const int*)d_in[9];

    // Workspace: G1h fp16 (4.19 MB, [y][bh][x] float4) | ghat fp16 (8.39 MB)
    char* ws = (char*)d_ws;
    float4* G1h4 = (float4*)ws;
    float2* gh   = (float2*)(ws + (size_t)HD * GXD * BD * sizeof(__half2));

    rowfft_kernel<<<512, 256, 0, stream>>>(xr, xi, sc_y, sc_x, G1h4);
    colfft_kernel<<<1024, 256, 0, stream>>>(G1h4, gh);
    gather_kernel<<<NSAMP / 32, 256, 0, stream>>>(
        (const __half2*)gh, wy, wx, phr, phi, iy, ix, (float2*)d_out);
}